// Round 19
// baseline (36.586 us; speedup 1.0000x reference)
//
#include <hip/hip_runtime.h>
#include <math.h>

#define NROWS 128
#define KDIM  1024
#define ODIM  512
#define NB    32
#define BS    32

__device__ __forceinline__ int clz32(unsigned x) { return x ? __builtin_clz(x) : 32; }

// FROZEN SEMANTICS (r15-r18): kept = (t & ~m) - (h & ~m), ~m = -1<<dr,
// h=P>>1, t=P+h, dr = clamp(isum - clz(t^h), 0, 31), P = ix*iw (|.|<=127),
// isum = in + s.  r19: full element pipeline in ONE 12-inst non-volatile asm
// block — removes compiler<->asm operand handoffs (the glue) at all 128 call
// sites/thread while keeping per-element granularity (4 independent chains
// per j-iter still schedulable; r12's monolithic-volatile mistake avoided).
// Hand-asm: immune to the r3/r4/r6 compiler mis-fold.  %9 = all-ones VGPR.
__device__ __forceinline__ int naf_elem(int ix, int iw, int in_, int s, int allones) {
  int kept, h, t, c, dr;
  asm("v_mul_i32_i24 %0, %5, %6\n\t"   // P  = ix * iw      (kept reg as temp)
      "v_add_u32     %4, %7, %8\n\t"   // dr = in + s       (isum, dr as temp)
      "v_ashrrev_i32 %1, 1, %0\n\t"    // h  = P >> 1 (arith)
      "v_add_u32     %2, %0, %1\n\t"   // t  = P + h
      "v_xor_b32     %3, %2, %1\n\t"   // c  = t ^ h
      "v_ffbh_u32    %3, %3\n\t"       // c  = clz(c)
      "v_sub_u32     %4, %4, %3\n\t"   // dr = isum - clz
      "v_med3_i32    %4, %4, 0, 31\n\t"// dr = clamp(dr, 0, 31)
      "v_lshlrev_b32 %3, %4, %9\n\t"   // c  = ~m = (-1) << dr
      "v_and_b32     %2, %2, %3\n\t"   // t &= ~m
      "v_and_b32     %1, %1, %3\n\t"   // h &= ~m
      "v_sub_u32     %0, %2, %1"       // kept = (t&~m) - (h&~m)
      : "=&v"(kept), "=&v"(h), "=&v"(t), "=&v"(c), "=&v"(dr)
      : "v"(ix), "v"(iw), "v"(in_), "v"(s), "v"(allones));
  return kept;
}

// ---------------- prep (r16-identical): coalesced via LDS transpose.
__global__ __launch_bounds__(64)
void prep_kernel(const float* __restrict__ x, const float* __restrict__ wgt,
                 unsigned short* __restrict__ xp, unsigned char* __restrict__ wq,
                 float* __restrict__ xs, float* __restrict__ lxs,
                 float* __restrict__ wsc, float* __restrict__ lws) {
  __shared__ float sl[2112];                      // 2048 + 64 pad
  const int b = blockIdx.x;
  const int lane = threadIdx.x;                   // 0..63
  const bool isx = b < 64;
  const float* src = isx ? (x + (size_t)b * 2048)
                         : (wgt + (size_t)(b - 64) * 2048);
#pragma unroll
  for (int j = 0; j < 8; ++j) {
    float4 f = ((const float4*)src)[j * 64 + lane];
    int f0 = (j * 64 + lane) * 4;
    int s0 = f0 + (f0 >> 5);                      // pad: +1 slot per 32 floats
    sl[s0] = f.x; sl[s0 + 1] = f.y; sl[s0 + 2] = f.z; sl[s0 + 3] = f.w;
  }
  __syncthreads();

  float v[32];
  float m = 0.f;
#pragma unroll
  for (int k = 0; k < 32; ++k) {
    v[k] = sl[lane * 33 + k];
    m = fmaxf(m, fabsf(v[k]));                    // max: order-exact
  }
  const float scale = fmaxf(m / 1.984375f, 1e-30f);
  const int gt = (isx ? b : (b - 64)) * 64 + lane;
  const int row = gt >> 5, blk = gt & 31;

  if (isx) {
    int q[32], e[32], emax = -60;
#pragma unroll
    for (int i = 0; i < 32; ++i) {
      float t = v[i] / scale * 64.0f;     // IEEE div + exact pow2 mul, matches ref
      int qi = (int)rintf(t);             // round-half-even, matches jnp.round
      q[i] = qi;
      int a = qi < 0 ? -qi : qi;
      int ei = a ? (31 - clz32((unsigned)a)) - 6 : -60;
      e[i] = ei;
      emax = ei > emax ? ei : emax;
    }
    unsigned short u[32];
#pragma unroll
    for (int i = 0; i < 32; ++i)
      u[i] = (unsigned short)(((emax - e[i]) << 8) | (q[i] & 0xFF));
    uint4* dst = (uint4*)(xp + (size_t)row * KDIM + blk * BS);
#pragma unroll
    for (int i = 0; i < 4; ++i) {
      uint4 w4;
      w4.x = (unsigned)u[8*i+0] | ((unsigned)u[8*i+1] << 16);
      w4.y = (unsigned)u[8*i+2] | ((unsigned)u[8*i+3] << 16);
      w4.z = (unsigned)u[8*i+4] | ((unsigned)u[8*i+5] << 16);
      w4.w = (unsigned)u[8*i+6] | ((unsigned)u[8*i+7] << 16);
      dst[i] = w4;
    }
    xs[gt] = scale;
    lxs[gt] = (float)log2((double)scale);
  } else {
    unsigned char c[32];
#pragma unroll
    for (int i = 0; i < 32; ++i) {
      float t = v[i] / scale * 64.0f;
      int qi = (int)rintf(t);
      c[i] = (unsigned char)(qi & 0xFF);
    }
    uint4* dst = (uint4*)(wq + (size_t)row * KDIM + blk * BS);
#pragma unroll
    for (int i = 0; i < 2; ++i) {
      uint4 w4;
      w4.x = (unsigned)c[16*i+ 0] | ((unsigned)c[16*i+ 1] << 8) | ((unsigned)c[16*i+ 2] << 16) | ((unsigned)c[16*i+ 3] << 24);
      w4.y = (unsigned)c[16*i+ 4] | ((unsigned)c[16*i+ 5] << 8) | ((unsigned)c[16*i+ 6] << 16) | ((unsigned)c[16*i+ 7] << 24);
      w4.z = (unsigned)c[16*i+ 8] | ((unsigned)c[16*i+ 9] << 8) | ((unsigned)c[16*i+10] << 16) | ((unsigned)c[16*i+11] << 24);
      w4.w = (unsigned)c[16*i+12] | ((unsigned)c[16*i+13] << 8) | ((unsigned)c[16*i+14] << 16) | ((unsigned)c[16*i+15] << 24);
      dst[i] = w4;
    }
    wsc[gt] = scale;
    lws[gt] = (float)log2((double)scale);
  }
}

// ---------------- main (r17/r18 structure): 8n x 16o tile, 16-way K-split,
// 2-o register blocking, e_max hoisted to sE table.
__global__ __launch_bounds__(1024, 8)
void msd_main_kernel(const unsigned short* __restrict__ xp,
                     const unsigned char* __restrict__ wq,
                     const float* __restrict__ xs, const float* __restrict__ lxs,
                     const float* __restrict__ wsc, const float* __restrict__ lws,
                     const float* __restrict__ bias, float* __restrict__ out) {
  __shared__ unsigned short sx[8][1032];    // row stride 2064B -> banks 4*tn
  __shared__ unsigned char  swq[16][1040];  // 2-way conflict only (free)
  __shared__ float sxs[8][33], slx[8][33], sws[16][33], slw[16][33];
  __shared__ int   sE[8][17];               // sbase(n,o) table
  __shared__ float sred[15 * 128];
  const int tid = threadIdx.x;
  const int n0 = blockIdx.x * 8, o0 = blockIdx.y * 16;

  // stage x tile: 8 rows x 1024 packed ushorts (1 uint4 per thread)
  {
    int r = tid >> 7, c = tid & 127;
    uint4 d = ((const uint4*)(xp + (size_t)(n0 + r) * KDIM))[c];
    *(uint4*)&sx[r][c * 8] = d;
  }
  // stage w tile: 16 rows x 1024 bytes (1 uint4 per thread)
  {
    int r = tid >> 6, c = tid & 63;
    uint4 d = ((const uint4*)(wq + (size_t)(o0 + r) * KDIM))[c];
    *(uint4*)&swq[r][c * 16] = d;
  }
  {
    int r = tid >> 5, b = tid & 31;
    if (tid < 256) {
      sxs[r][b] = xs[(n0 + r) * NB + b];
      slx[r][b] = lxs[(n0 + r) * NB + b];
    }
    if (tid < 512) {
      sws[r][b] = wsc[(o0 + r) * NB + b];
      slw[r][b] = lws[(o0 + r) * NB + b];
    }
  }
  __syncthreads();

  // e_max preamble once per (tn,to) by first 128 threads (was 8x redundant)
  if (tid < 128) {
    const int tn2 = tid >> 4, to2 = tid & 15;
    float emf = -1e30f;
#pragma unroll
    for (int b = 0; b < NB; ++b)
      emf = fmaxf(emf, floorf(slx[tn2][b] + slw[to2][b]));
    const int iemax = (int)emf;
    sE[tn2][to2] = 24 + (iemax < 0 ? iemax : 0);   // sbase
  }
  __syncthreads();

  const int kh = tid >> 6, idx = tid & 63, tn = idx >> 3, toa = idx & 7;
  const int tob = toa + 8;
  const int sbase_a = sE[tn][toa], sbase_b = sE[tn][tob];
  const int allones = (int)0xFFFFFFFF;   // feeds asm %9

  float facc_a = 0.f, facc_b = 0.f;
  const int b0 = kh * 2;
#pragma unroll
  for (int bb = 0; bb < 2; ++bb) {
    const int b = b0 + bb;
    const int s_a = sbase_a - (int)floorf(slx[tn][b] + slw[toa][b]);
    const int s_b = sbase_b - (int)floorf(slx[tn][b] + slw[tob][b]);
    const float cf_a = sxs[tn][b] * sws[toa][b];
    const float cf_b = sxs[tn][b] * sws[tob][b];
    int bacc_a = 0, bacc_b = 0;
#pragma unroll
    for (int hh = 0; hh < 2; ++hh) {     // half-blocks: bounded VGPR pressure
      const uint4 xu0 = *(const uint4*)&sx[tn][b * 32 + hh * 16];
      const uint4 xu1 = *(const uint4*)&sx[tn][b * 32 + hh * 16 + 8];
      const uint4 wau = *(const uint4*)&swq[toa][b * 32 + hh * 16];
      const uint4 wbu = *(const uint4*)&swq[tob][b * 32 + hh * 16];
      const unsigned xw8[8] = {xu0.x, xu0.y, xu0.z, xu0.w,
                               xu1.x, xu1.y, xu1.z, xu1.w};
      const unsigned wa4[4] = {wau.x, wau.y, wau.z, wau.w};
      const unsigned wb4[4] = {wbu.x, wbu.y, wbu.z, wbu.w};
#pragma unroll
      for (int j = 0; j < 8; ++j) {      // 2 elems per x-word, 2 o-cols each
        const unsigned xw = xw8[j];
        const unsigned wwa = wa4[j >> 1];
        const unsigned wwb = wb4[j >> 1];
        const int ix0 = __builtin_amdgcn_sbfe((int)xw, 0, 8);
        const int in0 = (int)__builtin_amdgcn_ubfe(xw, 8, 8);
        const int ix1 = __builtin_amdgcn_sbfe((int)xw, 16, 8);
        const int in1 = (int)(xw >> 24);
        int iwa0, iwa1, iwb0, iwb1;
        if (j & 1) { iwa0 = __builtin_amdgcn_sbfe((int)wwa, 16, 8);
                     iwa1 = __builtin_amdgcn_sbfe((int)wwa, 24, 8);
                     iwb0 = __builtin_amdgcn_sbfe((int)wwb, 16, 8);
                     iwb1 = __builtin_amdgcn_sbfe((int)wwb, 24, 8); }
        else       { iwa0 = __builtin_amdgcn_sbfe((int)wwa, 0, 8);
                     iwa1 = __builtin_amdgcn_sbfe((int)wwa, 8, 8);
                     iwb0 = __builtin_amdgcn_sbfe((int)wwb, 0, 8);
                     iwb1 = __builtin_amdgcn_sbfe((int)wwb, 8, 8); }
        bacc_a += naf_elem(ix0, iwa0, in0, s_a, allones);
        bacc_a += naf_elem(ix1, iwa1, in1, s_a, allones);
        bacc_b += naf_elem(ix0, iwb0, in0, s_b, allones);
        bacc_b += naf_elem(ix1, iwb1, in1, s_b, allones);
      }
    }
    facc_a += cf_a * (float)bacc_a;      // exact: block_dot = bacc/4096
    facc_b += cf_b * (float)bacc_b;
  }

  const int oa = tn * 16 + toa, ob = oa + 8;
  if (kh) {
    sred[(kh - 1) * 128 + oa] = facc_a;
    sred[(kh - 1) * 128 + ob] = facc_b;
  }
  __syncthreads();
  if (!kh) {
    float ra = facc_a, rb = facc_b;
#pragma unroll
    for (int p = 0; p < 15; ++p) {
      ra += sred[p * 128 + oa];
      rb += sred[p * 128 + ob];
    }
    out[(size_t)(n0 + tn) * ODIM + (o0 + toa)] = ra * (1.0f / 4096.0f) + bias[o0 + toa];
    out[(size_t)(n0 + tn) * ODIM + (o0 + tob)] = rb * (1.0f / 4096.0f) + bias[o0 + tob];
  }
}

extern "C" void kernel_launch(void* const* d_in, const int* in_sizes, int n_in,
                              void* d_out, int out_size, void* d_ws, size_t ws_size,
                              hipStream_t stream) {
  const float* x    = (const float*)d_in[0];
  const float* wgt  = (const float*)d_in[1];
  const float* bias = (const float*)d_in[2];
  float* out = (float*)d_out;
  char* ws = (char*)d_ws;
  // workspace layout (16B-aligned)
  unsigned short* xp  = (unsigned short*)(ws + 0);       // 262144 B
  unsigned char*  wq  = (unsigned char*)(ws + 262144);   // 524288 B
  float* xs  = (float*)(ws + 786432);
  float* lxs = (float*)(ws + 802816);
  float* wsc = (float*)(ws + 819200);
  float* lws = (float*)(ws + 884736);

  hipLaunchKernelGGL(prep_kernel, dim3(320), dim3(64), 0, stream,
                     x, wgt, xp, wq, xs, lxs, wsc, lws);
  hipLaunchKernelGGL(msd_main_kernel, dim3(16, 32), dim3(1024), 0, stream,
                     xp, wq, xs, lxs, wsc, lws, bias, out);
}

// Round 20
// 33.926 us; speedup vs baseline: 1.0784x; 1.0784x over previous
//
#include <hip/hip_runtime.h>
#include <math.h>

#define NROWS 128
#define KDIM  1024
#define ODIM  512
#define NB    32
#define BS    32

__device__ __forceinline__ int clz32(unsigned x) { return x ? __builtin_clz(x) : 32; }

// FROZEN (r15/r18-verified optimum): 10-inst non-volatile asm core.
// kept = (t & ~m) - (h & ~m), ~m = -1<<dr, h=P>>1, t=P+h,
// dr = clamp(isum - clz(t^h), 0, 31).  Exact by bit-partition; P=0 -> kept=0.
// Hand-asm: immune to the r3/r4/r6 compiler mis-fold.  %7 = all-ones VGPR.
// Granularity is the measured optimum: fused-pair (r12, -5.3us) and
// widened 12-inst (r19, -2.5us) both regress.
__device__ __forceinline__ int naf_keep(int P, int isum, int allones) {
  int kept, h, t, c, dr;
  asm("v_ashrrev_i32 %1, 1, %5\n\t"     // h  = P >> 1 (arith)
      "v_add_u32     %2, %5, %1\n\t"    // t  = P + h
      "v_xor_b32     %3, %2, %1\n\t"    // c  = t ^ h
      "v_ffbh_u32    %3, %3\n\t"        // c  = clz(c)
      "v_sub_u32     %4, %6, %3\n\t"    // dr = isum - c
      "v_med3_i32    %4, %4, 0, 31\n\t" // dr = clamp(dr, 0, 31)
      "v_lshlrev_b32 %3, %4, %7\n\t"    // c  = ~m = (-1) << dr
      "v_and_b32     %2, %2, %3\n\t"    // t &= ~m
      "v_and_b32     %1, %1, %3\n\t"    // h &= ~m
      "v_sub_u32     %0, %2, %1"        // kept = (t&~m) - (h&~m)
      : "=v"(kept), "=&v"(h), "=&v"(t), "=&v"(c), "=&v"(dr)
      : "v"(P), "v"(isum), "v"(allones));
  return kept;
}

// ---------------- prep (r16-identical): coalesced via LDS transpose.
__global__ __launch_bounds__(64)
void prep_kernel(const float* __restrict__ x, const float* __restrict__ wgt,
                 unsigned short* __restrict__ xp, unsigned char* __restrict__ wq,
                 float* __restrict__ xs, float* __restrict__ lxs,
                 float* __restrict__ wsc, float* __restrict__ lws) {
  __shared__ float sl[2112];                      // 2048 + 64 pad
  const int b = blockIdx.x;
  const int lane = threadIdx.x;                   // 0..63
  const bool isx = b < 64;
  const float* src = isx ? (x + (size_t)b * 2048)
                         : (wgt + (size_t)(b - 64) * 2048);
#pragma unroll
  for (int j = 0; j < 8; ++j) {
    float4 f = ((const float4*)src)[j * 64 + lane];
    int f0 = (j * 64 + lane) * 4;
    int s0 = f0 + (f0 >> 5);                      // pad: +1 slot per 32 floats
    sl[s0] = f.x; sl[s0 + 1] = f.y; sl[s0 + 2] = f.z; sl[s0 + 3] = f.w;
  }
  __syncthreads();

  float v[32];
  float m = 0.f;
#pragma unroll
  for (int k = 0; k < 32; ++k) {
    v[k] = sl[lane * 33 + k];
    m = fmaxf(m, fabsf(v[k]));                    // max: order-exact
  }
  const float scale = fmaxf(m / 1.984375f, 1e-30f);
  const int gt = (isx ? b : (b - 64)) * 64 + lane;
  const int row = gt >> 5, blk = gt & 31;

  if (isx) {
    int q[32], e[32], emax = -60;
#pragma unroll
    for (int i = 0; i < 32; ++i) {
      float t = v[i] / scale * 64.0f;     // IEEE div + exact pow2 mul, matches ref
      int qi = (int)rintf(t);             // round-half-even, matches jnp.round
      q[i] = qi;
      int a = qi < 0 ? -qi : qi;
      int ei = a ? (31 - clz32((unsigned)a)) - 6 : -60;
      e[i] = ei;
      emax = ei > emax ? ei : emax;
    }
    unsigned short u[32];
#pragma unroll
    for (int i = 0; i < 32; ++i)
      u[i] = (unsigned short)(((emax - e[i]) << 8) | (q[i] & 0xFF));
    uint4* dst = (uint4*)(xp + (size_t)row * KDIM + blk * BS);
#pragma unroll
    for (int i = 0; i < 4; ++i) {
      uint4 w4;
      w4.x = (unsigned)u[8*i+0] | ((unsigned)u[8*i+1] << 16);
      w4.y = (unsigned)u[8*i+2] | ((unsigned)u[8*i+3] << 16);
      w4.z = (unsigned)u[8*i+4] | ((unsigned)u[8*i+5] << 16);
      w4.w = (unsigned)u[8*i+6] | ((unsigned)u[8*i+7] << 16);
      dst[i] = w4;
    }
    xs[gt] = scale;
    lxs[gt] = (float)log2((double)scale);
  } else {
    unsigned char c[32];
#pragma unroll
    for (int i = 0; i < 32; ++i) {
      float t = v[i] / scale * 64.0f;
      int qi = (int)rintf(t);
      c[i] = (unsigned char)(qi & 0xFF);
    }
    uint4* dst = (uint4*)(wq + (size_t)row * KDIM + blk * BS);
#pragma unroll
    for (int i = 0; i < 2; ++i) {
      uint4 w4;
      w4.x = (unsigned)c[16*i+ 0] | ((unsigned)c[16*i+ 1] << 8) | ((unsigned)c[16*i+ 2] << 16) | ((unsigned)c[16*i+ 3] << 24);
      w4.y = (unsigned)c[16*i+ 4] | ((unsigned)c[16*i+ 5] << 8) | ((unsigned)c[16*i+ 6] << 16) | ((unsigned)c[16*i+ 7] << 24);
      w4.z = (unsigned)c[16*i+ 8] | ((unsigned)c[16*i+ 9] << 8) | ((unsigned)c[16*i+10] << 16) | ((unsigned)c[16*i+11] << 24);
      w4.w = (unsigned)c[16*i+12] | ((unsigned)c[16*i+13] << 8) | ((unsigned)c[16*i+14] << 16) | ((unsigned)c[16*i+15] << 24);
      dst[i] = w4;
    }
    wsc[gt] = scale;
    lws[gt] = (float)log2((double)scale);
  }
}

// ---------------- main (r18-identical): 8n x 16o tile, 16-way K-split,
// 2-o register blocking, e_max hoisted to sE table.
__global__ __launch_bounds__(1024, 8)
void msd_main_kernel(const unsigned short* __restrict__ xp,
                     const unsigned char* __restrict__ wq,
                     const float* __restrict__ xs, const float* __restrict__ lxs,
                     const float* __restrict__ wsc, const float* __restrict__ lws,
                     const float* __restrict__ bias, float* __restrict__ out) {
  __shared__ unsigned short sx[8][1032];    // row stride 2064B -> banks 4*tn
  __shared__ unsigned char  swq[16][1040];  // 2-way conflict only (free)
  __shared__ float sxs[8][33], slx[8][33], sws[16][33], slw[16][33];
  __shared__ int   sE[8][17];               // sbase(n,o) table
  __shared__ float sred[15 * 128];
  const int tid = threadIdx.x;
  const int n0 = blockIdx.x * 8, o0 = blockIdx.y * 16;

  // stage x tile: 8 rows x 1024 packed ushorts (1 uint4 per thread)
  {
    int r = tid >> 7, c = tid & 127;
    uint4 d = ((const uint4*)(xp + (size_t)(n0 + r) * KDIM))[c];
    *(uint4*)&sx[r][c * 8] = d;
  }
  // stage w tile: 16 rows x 1024 bytes (1 uint4 per thread)
  {
    int r = tid >> 6, c = tid & 63;
    uint4 d = ((const uint4*)(wq + (size_t)(o0 + r) * KDIM))[c];
    *(uint4*)&swq[r][c * 16] = d;
  }
  {
    int r = tid >> 5, b = tid & 31;
    if (tid < 256) {
      sxs[r][b] = xs[(n0 + r) * NB + b];
      slx[r][b] = lxs[(n0 + r) * NB + b];
    }
    if (tid < 512) {
      sws[r][b] = wsc[(o0 + r) * NB + b];
      slw[r][b] = lws[(o0 + r) * NB + b];
    }
  }
  __syncthreads();

  // e_max preamble once per (tn,to) by first 128 threads (was 8x redundant)
  if (tid < 128) {
    const int tn2 = tid >> 4, to2 = tid & 15;
    float emf = -1e30f;
#pragma unroll
    for (int b = 0; b < NB; ++b)
      emf = fmaxf(emf, floorf(slx[tn2][b] + slw[to2][b]));
    const int iemax = (int)emf;
    sE[tn2][to2] = 24 + (iemax < 0 ? iemax : 0);   // sbase
  }
  __syncthreads();

  const int kh = tid >> 6, idx = tid & 63, tn = idx >> 3, toa = idx & 7;
  const int tob = toa + 8;
  const int sbase_a = sE[tn][toa], sbase_b = sE[tn][tob];
  const int allones = (int)0xFFFFFFFF;   // feeds asm %7

  float facc_a = 0.f, facc_b = 0.f;
  const int b0 = kh * 2;
#pragma unroll
  for (int bb = 0; bb < 2; ++bb) {
    const int b = b0 + bb;
    const int s_a = sbase_a - (int)floorf(slx[tn][b] + slw[toa][b]);
    const int s_b = sbase_b - (int)floorf(slx[tn][b] + slw[tob][b]);
    const float cf_a = sxs[tn][b] * sws[toa][b];
    const float cf_b = sxs[tn][b] * sws[tob][b];
    int bacc_a = 0, bacc_b = 0;
#pragma unroll
    for (int hh = 0; hh < 2; ++hh) {     // half-blocks: bounded VGPR pressure
      const uint4 xu0 = *(const uint4*)&sx[tn][b * 32 + hh * 16];
      const uint4 xu1 = *(const uint4*)&sx[tn][b * 32 + hh * 16 + 8];
      const uint4 wau = *(const uint4*)&swq[toa][b * 32 + hh * 16];
      const uint4 wbu = *(const uint4*)&swq[tob][b * 32 + hh * 16];
      const unsigned xw8[8] = {xu0.x, xu0.y, xu0.z, xu0.w,
                               xu1.x, xu1.y, xu1.z, xu1.w};
      const unsigned wa4[4] = {wau.x, wau.y, wau.z, wau.w};
      const unsigned wb4[4] = {wbu.x, wbu.y, wbu.z, wbu.w};
#pragma unroll
      for (int j = 0; j < 8; ++j) {      // 2 elems per x-word, 2 o-cols each
        const unsigned xw = xw8[j];
        const unsigned wwa = wa4[j >> 1];
        const unsigned wwb = wb4[j >> 1];
        const int ix0 = __builtin_amdgcn_sbfe((int)xw, 0, 8);
        const int in0 = (int)__builtin_amdgcn_ubfe(xw, 8, 8);
        const int ix1 = __builtin_amdgcn_sbfe((int)xw, 16, 8);
        const int in1 = (int)(xw >> 24);
        int iwa0, iwa1, iwb0, iwb1;
        if (j & 1) { iwa0 = __builtin_amdgcn_sbfe((int)wwa, 16, 8);
                     iwa1 = __builtin_amdgcn_sbfe((int)wwa, 24, 8);
                     iwb0 = __builtin_amdgcn_sbfe((int)wwb, 16, 8);
                     iwb1 = __builtin_amdgcn_sbfe((int)wwb, 24, 8); }
        else       { iwa0 = __builtin_amdgcn_sbfe((int)wwa, 0, 8);
                     iwa1 = __builtin_amdgcn_sbfe((int)wwa, 8, 8);
                     iwb0 = __builtin_amdgcn_sbfe((int)wwb, 0, 8);
                     iwb1 = __builtin_amdgcn_sbfe((int)wwb, 8, 8); }
        bacc_a += naf_keep(__mul24(ix0, iwa0), in0 + s_a, allones);
        bacc_a += naf_keep(__mul24(ix1, iwa1), in1 + s_a, allones);
        bacc_b += naf_keep(__mul24(ix0, iwb0), in0 + s_b, allones);
        bacc_b += naf_keep(__mul24(ix1, iwb1), in1 + s_b, allones);
      }
    }
    facc_a += cf_a * (float)bacc_a;      // exact: block_dot = bacc/4096
    facc_b += cf_b * (float)bacc_b;
  }

  const int oa = tn * 16 + toa, ob = oa + 8;
  if (kh) {
    sred[(kh - 1) * 128 + oa] = facc_a;
    sred[(kh - 1) * 128 + ob] = facc_b;
  }
  __syncthreads();
  if (!kh) {
    float ra = facc_a, rb = facc_b;
#pragma unroll
    for (int p = 0; p < 15; ++p) {
      ra += sred[p * 128 + oa];
      rb += sred[p * 128 + ob];
    }
    out[(size_t)(n0 + tn) * ODIM + (o0 + toa)] = ra * (1.0f / 4096.0f) + bias[o0 + toa];
    out[(size_t)(n0 + tn) * ODIM + (o0 + tob)] = rb * (1.0f / 4096.0f) + bias[o0 + tob];
  }
}

extern "C" void kernel_launch(void* const* d_in, const int* in_sizes, int n_in,
                              void* d_out, int out_size, void* d_ws, size_t ws_size,
                              hipStream_t stream) {
  const float* x    = (const float*)d_in[0];
  const float* wgt  = (const float*)d_in[1];
  const float* bias = (const float*)d_in[2];
  float* out = (float*)d_out;
  char* ws = (char*)d_ws;
  // workspace layout (16B-aligned)
  unsigned short* xp  = (unsigned short*)(ws + 0);       // 262144 B
  unsigned char*  wq  = (unsigned char*)(ws + 262144);   // 524288 B
  float* xs  = (float*)(ws + 786432);
  float* lxs = (float*)(ws + 802816);
  float* wsc = (float*)(ws + 819200);
  float* lws = (float*)(ws + 884736);

  hipLaunchKernelGGL(prep_kernel, dim3(320), dim3(64), 0, stream,
                     x, wgt, xp, wq, xs, lxs, wsc, lws);
  hipLaunchKernelGGL(msd_main_kernel, dim3(16, 32), dim3(1024), 0, stream,
                     xp, wq, xs, lxs, wsc, lws, bias, out);
}